// Round 1
// baseline (478.101 us; speedup 1.0000x reference)
//
#include <hip/hip_runtime.h>

// Batched inverse of 3x3 upper-triangular matrices stored as rows of 9 floats.
// Only elements 0,1,2,4,5,8 are read; output is the row-major flattened inverse.
//
// Memory-bound problem: 302 MB in + 302 MB out => ~96 us floor at 6.3 TB/s.
// Pattern: LDS-staged block transpose so all global traffic is float4-coalesced.
//  - 256 rows/block = 2304 floats = 576 float4 (block byte base 9216 % 16 == 0)
//  - LDS compute-phase reads at stride 9 (coprime with 32 banks) => 2-way
//    aliasing only, which is free on gfx950 (m136).
//  - compute reads+writes its own 9-float slice => no sync between read/write.

#define THREADS 256
#define ROWS_PER_BLOCK 256
#define FLTS_PER_BLOCK (ROWS_PER_BLOCK * 9)   // 2304
#define VEC4_PER_BLOCK (FLTS_PER_BLOCK / 4)   // 576

__global__ __launch_bounds__(THREADS) void inv3x3_kernel(
    const float* __restrict__ x, float* __restrict__ out, int n_rows) {
    __shared__ float s[FLTS_PER_BLOCK];

    const int tid = threadIdx.x;
    const long long row0 = (long long)blockIdx.x * ROWS_PER_BLOCK;
    const long long base = row0 * 9;  // flat float offset of this block
    const int rows = min(ROWS_PER_BLOCK, n_rows - (int)row0);

    if (rows == ROWS_PER_BLOCK) {
        // ---- fast path: full block, fully vectorized ----
        const float4* __restrict__ in4 = reinterpret_cast<const float4*>(x + base);
        float4* s4 = reinterpret_cast<float4*>(s);
        s4[tid]       = in4[tid];
        s4[tid + 256] = in4[tid + 256];
        if (tid < VEC4_PER_BLOCK - 512) s4[tid + 512] = in4[tid + 512];
        __syncthreads();

        float* row = s + tid * 9;
        const float a = row[0], b = row[1], c = row[2];
        const float d = row[4], e = row[5];
        const float f = row[8];
        const float ia  = 1.0f / a;
        const float idd = 1.0f / d;
        const float iff = 1.0f / f;
        const float o01 = -b * ia * idd;
        const float o12 = -e * idd * iff;
        const float o02 = (b * e - c * d) * (ia * idd * iff);
        // in-place: this thread's own slice only => no barrier needed here
        row[0] = ia;   row[1] = o01;  row[2] = o02;
        row[3] = 0.0f; row[4] = idd;  row[5] = o12;
        row[6] = 0.0f; row[7] = 0.0f; row[8] = iff;
        __syncthreads();

        float4* __restrict__ o4 = reinterpret_cast<float4*>(out + base);
        o4[tid]       = s4[tid];
        o4[tid + 256] = s4[tid + 256];
        if (tid < VEC4_PER_BLOCK - 512) o4[tid + 512] = s4[tid + 512];
    } else {
        // ---- tail path: scalar, bounds-checked (unused when N % 256 == 0) ----
        const long long r = row0 + tid;
        if (tid < rows && r < n_rows) {
            const float* p = x + r * 9;
            const float a = p[0], b = p[1], c = p[2];
            const float d = p[4], e = p[5];
            const float f = p[8];
            const float ia  = 1.0f / a;
            const float idd = 1.0f / d;
            const float iff = 1.0f / f;
            float* q = out + r * 9;
            q[0] = ia;   q[1] = -b * ia * idd;  q[2] = (b * e - c * d) * (ia * idd * iff);
            q[3] = 0.0f; q[4] = idd;            q[5] = -e * idd * iff;
            q[6] = 0.0f; q[7] = 0.0f;           q[8] = iff;
        }
    }
}

extern "C" void kernel_launch(void* const* d_in, const int* in_sizes, int n_in,
                              void* d_out, int out_size, void* d_ws, size_t ws_size,
                              hipStream_t stream) {
    const float* x = (const float*)d_in[0];
    float* out = (float*)d_out;
    const int n_rows = in_sizes[0] / 9;
    const int blocks = (n_rows + ROWS_PER_BLOCK - 1) / ROWS_PER_BLOCK;
    inv3x3_kernel<<<blocks, THREADS, 0, stream>>>(x, out, n_rows);
}